// Round 16
// baseline (1001.449 us; speedup 1.0000x reference)
//
#include <hip/hip_runtime.h>

#define EPS 1e-5f
#define SELU_L 1.0507009873554805f
#define SELU_A 1.6732632423543772f
#define SELU_LA (SELU_L * SELU_A)

typedef _Float16 half8 __attribute__((ext_vector_type(8)));
typedef _Float16 half4 __attribute__((ext_vector_type(4)));
typedef float floatx4 __attribute__((ext_vector_type(4)));

__device__ __forceinline__ float selu_f(float x) {
    return x > 0.f ? SELU_L * x : SELU_LA * (__expf(x) - 1.f);
}

// async global->LDS, 16B per lane; LDS dest is wave-uniform base + lane*16
__device__ __forceinline__ void gload_lds16(const _Float16* g, _Float16* l) {
    __builtin_amdgcn_global_load_lds(
        (const __attribute__((address_space(1))) void*)g,
        (__attribute__((address_space(3))) void*)l, 16, 0, 0);
}

// ------------- weight swizzle prep: A-operand fragment order, fp16 -------------
// wb_h : [t=18][mi=4][L=64][j=8]  co = mi*16 + (L&15), ci = (t&1)*32 + (L>>4)*8 + j, s = t>>1
// wb_in: [mi=4][L=64][j=8]        k = (L>>4)*8+j -> s=k/3, ci=k%3 (k>=27 -> 0)
// wb_out:[t=18][L=64][j=8]        co = L&15 (valid <3), ci/s as wb_h
// zp   : 256 halves of zeros (OOB redirect target for global_load_lds staging)
// bar  : grid-barrier counter (ws is poisoned between runs -> zeroed here)
__global__ __launch_bounds__(256) void k_prep(
    const float* __restrict__ w_h, const float* __restrict__ w_in,
    const float* __restrict__ w_out, _Float16* __restrict__ wb_h,
    _Float16* __restrict__ wb_in, _Float16* __restrict__ wb_out,
    _Float16* __restrict__ zp, unsigned* __restrict__ bar)
{
    int i = blockIdx.x * 256 + threadIdx.x;
    if (i == 0) *bar = 0u;
    if (i < 256) zp[i] = (_Float16)0.f;  // zero page
    if (i < 36864) {
        int t = i >> 11;
        int rem = i & 2047;
        int mi = rem >> 9;
        int L = (rem >> 3) & 63;
        int j = i & 7;
        int co = mi * 16 + (L & 15);
        int ci = ((t & 1) << 5) + ((L >> 4) << 3) + j;
        int s = t >> 1;
        wb_h[i] = (_Float16)w_h[(co * 64 + ci) * 9 + s];
    } else if (i < 36864 + 2048) {
        int e = i - 36864;
        int mi = e >> 9;
        int L = (e >> 3) & 63;
        int j = e & 7;
        int co = mi * 16 + (L & 15);
        int k = ((L >> 4) << 3) + j;
        _Float16 val = (_Float16)0.f;
        if (k < 27) {
            int s = k / 3, ci = k - s * 3;
            val = (_Float16)w_in[(co * 3 + ci) * 9 + s];
        }
        wb_in[e] = val;
    } else if (i < 36864 + 2048 + 9216) {
        int e = i - 36864 - 2048;
        int t = e >> 9;
        int L = (e >> 3) & 63;
        int j = e & 7;
        int co = L & 15;
        int ci = ((t & 1) << 5) + ((L >> 4) << 3) + j;
        int s = t >> 1;
        _Float16 val = (_Float16)0.f;
        if (co < 3) val = (_Float16)w_out[(co * 64 + ci) * 9 + s];
        wb_out[e] = val;
    }
}

// ------------- conv_in: 3 -> 64, BN, SELU, NHWC fp16 out (MFMA, K=32) -------------
__global__ __launch_bounds__(256) void k_conv_in_mfma(
    const float* __restrict__ X, const _Float16* __restrict__ wb,
    const float* __restrict__ bconv, const float* __restrict__ g,
    const float* __restrict__ be, const float* __restrict__ bm,
    const float* __restrict__ bv, _Float16* __restrict__ dst)
{
    __shared__ float s_x[3][18][18];
    __shared__ float s_sc[64], s_bs[64];
    const int tid = threadIdx.x;
    const int w0 = blockIdx.x * 16, h0 = blockIdx.y * 16, b = blockIdx.z;

    if (tid < 64) {
        float sc = g[tid] * rsqrtf(bv[tid] + EPS);
        s_sc[tid] = sc;
        s_bs[tid] = (bconv[tid] - bm[tid]) * sc + be[tid];
    }
    for (int idx = tid; idx < 3 * 324; idx += 256) {
        int ci = idx / 324, rem = idx - ci * 324;
        int r = rem / 18, c = rem - r * 18;
        int gh = h0 - 1 + r, gw = w0 - 1 + c;
        float val = 0.f;
        if ((unsigned)gh < 256u && (unsigned)gw < 256u)
            val = X[((b * 3 + ci) << 16) + (gh << 8) + gw];
        s_x[ci][r][c] = val;
    }
    __syncthreads();

    const int wv = tid >> 6, L = tid & 63, quad = L >> 4, l15 = L & 15;
    half8 a[4];
    #pragma unroll
    for (int mi = 0; mi < 4; ++mi)
        a[mi] = *(const half8*)(wb + (mi * 64 + L) * 8);

    floatx4 acc[4][4];
    #pragma unroll
    for (int mi = 0; mi < 4; ++mi)
        #pragma unroll
        for (int ni = 0; ni < 4; ++ni) acc[mi][ni] = (floatx4){0.f, 0.f, 0.f, 0.f};

    #pragma unroll
    for (int ni = 0; ni < 4; ++ni) {
        half8 bfr;
        #pragma unroll
        for (int j = 0; j < 8; ++j) {
            int k = quad * 8 + j;
            float xv = 0.f;
            if (k < 27) {
                int s = k / 3, ci = k - s * 3;
                int kh = s / 3, kw = s - kh * 3;
                xv = s_x[ci][wv * 4 + ni + kh][l15 + kw];
            }
            bfr[j] = (_Float16)xv;
        }
        #pragma unroll
        for (int mi = 0; mi < 4; ++mi)
            acc[mi][ni] = __builtin_amdgcn_mfma_f32_16x16x32_f16(a[mi], bfr, acc[mi][ni], 0, 0, 0);
    }

    _Float16* db = dst + ((size_t)b << 22);  // b*256*256*64
    #pragma unroll
    for (int mi = 0; mi < 4; ++mi) {
        const int cob = mi * 16 + quad * 4;
        floatx4 sc = *(const floatx4*)(&s_sc[cob]);
        floatx4 bs = *(const floatx4*)(&s_bs[cob]);
        #pragma unroll
        for (int ni = 0; ni < 4; ++ni) {
            half4 ov;
            #pragma unroll
            for (int r = 0; r < 4; ++r)
                ov[r] = (_Float16)selu_f(acc[mi][ni][r] * sc[r] + bs[r]);
            const int row = h0 + wv * 4 + ni, col = w0 + l15;
            *(half4*)(db + ((((row << 8) + col) << 6) + cob)) = ov;
        }
    }
}

// ------------- hidden mega v2: all 18 layers, v13 inner, POLITE grid barrier ----------
// (round 15 post-mortem: v13 null vs v9 -> compute partition exhausted; remaining
//  per-layer fixed cost = launch boundary + weight/BN prologue ~ 8-10 us/layer.
//  Round-7 mega eliminated those and PASSED correctness but its grid barrier was an
//  atomicAdd(bar,0) poll storm (~20 us/barrier fabric congestion). Fix: s_sleep(32)
//  between polls (~0.85 us) cuts RMW rate ~100x; fence/signal skeleton kept verbatim
//  from the round-7 passing kernel. Weights+BN staged ONCE for all 18 layers.
//  Co-residency structural: 158 KB LDS -> 1 block/CU, grid 256 = CU count.
//  Inner compute/staging/swizzle byte-identical v13 -> bit-identical output.)
__global__ __launch_bounds__(1024) void k_hidden_all(
    _Float16* __restrict__ act0, _Float16* __restrict__ act1,
    const _Float16* __restrict__ wb,
    const float* __restrict__ bconv, const float* __restrict__ g,
    const float* __restrict__ be, const float* __restrict__ bm,
    const float* __restrict__ bv, const _Float16* __restrict__ zp,
    unsigned* __restrict__ bar)
{
    __shared__ _Float16 s_w[36864];        // 73728 B: full weight set (all layers share)
    __shared__ _Float16 s_act[2][20992];   // 2 x 41984 B (41 wave-chunks incl. pad)
    __shared__ float s_sc[64], s_bs[64];
    const int tid = threadIdx.x;
    const int wv = tid >> 6, L = tid & 63, quad = L >> 4, l15 = L & 15;
    const int rq = wv >> 2, mq = wv & 3;   // row-quad (0..3), channel-quad (0..3)

    if (tid < 64) {
        float sc = g[tid] * rsqrtf(bv[tid] + EPS);
        s_sc[tid] = sc;
        s_bs[tid] = (bconv[tid] - bm[tid]) * sc + be[tid];
    }

    // ---- weights -> LDS ONCE for all 18 layers: 72 wave-chunks over 16 waves ----
    #pragma unroll
    for (int k = 0; k < 5; ++k) {
        const int wc = k * 16 + wv;
        if (wc < 72)
            gload_lds16(wb + ((wc << 6) + L) * 8, &s_w[wc << 9]);
    }

    // ---- stage one 18x18x64 halo tile (41 wave-chunks) over 16 waves ----
    auto stage = [&](const _Float16* sp, int tau, int buf) {
        const int b = tau >> 8, rem = tau & 255;
        const int h0 = (rem >> 4) << 4, w0 = (rem & 15) << 4;
        const _Float16* sb = sp + ((size_t)b << 22);
        #pragma unroll
        for (int k = 0; k < 3; ++k) {
            const int wc = k * 16 + wv;          // wave-uniform
            if (wc < 41) {
                const int p = (wc << 3) + (L >> 3);   // pixel (>=324 is pad)
                const int sd = (L & 7) ^ (p & 7);     // source chunk (pre-swizzle)
                const int rp = p / 18, cl = p - rp * 18;
                const int gh = h0 - 1 + rp, gw = w0 - 1 + cl;
                const _Float16* gp = (p < 324 && (unsigned)gh < 256u && (unsigned)gw < 256u)
                    ? sb + ((((gh << 8) + gw) << 6) + (sd << 3)) : zp;
                gload_lds16(gp, &s_act[buf][wc << 9]);
            }
        }
    };

    const int tau0 = blockIdx.x << 2;   // 4 consecutive tiles per block
    _Float16* src = act0;
    _Float16* dst = act1;

    stage(src, tau0, 0);
    __syncthreads();   // drains vmcnt: weights + tile0 staging complete

    for (int layer = 0; layer < 18; ++layer) {
        for (int ti = 0; ti < 4; ++ti) {
            const int tau = tau0 + ti, cur = ti & 1;
            if (ti < 3) stage(src, tau + 1, cur ^ 1);   // issue-early

            floatx4 acc[4];
            #pragma unroll
            for (int ni = 0; ni < 4; ++ni) acc[ni] = (floatx4){0.f, 0.f, 0.f, 0.f};

            const _Float16* bufp = &s_act[cur][0];
            #pragma unroll
            for (int h = 0; h < 2; ++h) {          // k-half (ci 0-31 / 32-63)
                const int sb8 = (h << 2) + quad;   // chunk slot within pixel
                #pragma unroll
                for (int kw = 0; kw < 3; ++kw) {
                    half8 ac[3];                   // A-cache: 3 kh for this ch-quad
                    #pragma unroll
                    for (int kh = 0; kh < 3; ++kh) {
                        const int t = ((kh * 3 + kw) << 1) + h;
                        ac[kh] = *(const half8*)(&s_w[((t * 4 + mq) * 64 + L) * 8]);
                    }
                    #pragma unroll
                    for (int j = 0; j < 6; ++j) {  // one B-read feeds <=3 MFMAs
                        const int p = (rq * 4 + j) * 18 + l15 + kw;
                        half8 bfr = *(const half8*)(bufp + (p << 6) + (((p & 7) ^ sb8) << 3));
                        #pragma unroll
                        for (int kh = 0; kh < 3; ++kh) {
                            const int ni = j - kh;
                            if (ni >= 0 && ni < 4)
                                acc[ni] = __builtin_amdgcn_mfma_f32_16x16x32_f16(ac[kh], bfr, acc[ni], 0, 0, 0);
                        }
                    }
                }
            }

            // epilogue: BN + SELU + NHWC store
            const int b = tau >> 8, rem = tau & 255;
            const int h0 = (rem >> 4) << 4, w0 = (rem & 15) << 4;
            _Float16* db = dst + ((size_t)b << 22);
            const int cob = mq * 16 + quad * 4;
            floatx4 sc = *(const floatx4*)(&s_sc[cob]);
            floatx4 bs = *(const floatx4*)(&s_bs[cob]);
            #pragma unroll
            for (int ni = 0; ni < 4; ++ni) {
                half4 ov;
                #pragma unroll
                for (int r = 0; r < 4; ++r)
                    ov[r] = (_Float16)selu_f(acc[ni][r] * sc[r] + bs[r]);
                const int row = h0 + rq * 4 + ni, col = w0 + l15;
                *(half4*)(db + ((((row << 8) + col) << 6) + cob)) = ov;
            }
            __syncthreads();   // buf[cur] free + all stores issued before signal
        }

        if (layer < 17) {
            // ---- polite grid barrier (256 co-resident blocks; round-7 skeleton) ----
            if (tid == 0) {
                __threadfence();                   // release: dst stores visible device-wide
                atomicAdd(bar, 1u);
                const unsigned tgt = 256u * (unsigned)(layer + 1);
                while (atomicAdd(bar, 0u) < tgt)
                    __builtin_amdgcn_s_sleep(32);  // ~0.85 us/poll: no RMW storm
                __threadfence();                   // acquire: invalidate stale cache
            }
            __syncthreads();

            _Float16* t = src; src = dst; dst = t;
            stage(src, tau0, 0);                   // tile0 of next layer
            __syncthreads();
        }
    }
}

// ------------- conv_out: 64 -> 3, BN, SELU, + interpolate_zeros(X), fp32 out -------------
__global__ __launch_bounds__(256) void k_conv_out_mfma(
    const _Float16* __restrict__ src, const _Float16* __restrict__ wb,
    const float* __restrict__ bconv, const float* __restrict__ g,
    const float* __restrict__ be, const float* __restrict__ bm,
    const float* __restrict__ bv, const float* __restrict__ X,
    float* __restrict__ out)
{
    __shared__ _Float16 s_in[324 * 72];
    const int tid = threadIdx.x;
    const int w0 = blockIdx.x * 16, h0 = blockIdx.y * 16, b = blockIdx.z;
    const _Float16* sb = src + ((size_t)b << 22);

    for (int idx = tid; idx < 2592; idx += 256) {
        int r = idx / 144, cpos = idx - r * 144;
        int col = cpos >> 3, sub = cpos & 7;
        int gh = h0 - 1 + r, gw = w0 - 1 + col;
        half8 val = {0, 0, 0, 0, 0, 0, 0, 0};
        if ((unsigned)gh < 256u && (unsigned)gw < 256u)
            val = *(const half8*)(sb + ((((gh << 8) + gw) << 6) + (sub << 3)));
        *(half8*)(&s_in[(r * 18 + col) * 72 + (sub << 3)]) = val;
    }
    __syncthreads();

    const int wv = tid >> 6, L = tid & 63, quad = L >> 4, l15 = L & 15;
    floatx4 acc[4];
    #pragma unroll
    for (int ni = 0; ni < 4; ++ni) acc[ni] = (floatx4){0.f, 0.f, 0.f, 0.f};

    #pragma unroll
    for (int t = 0; t < 18; ++t) {
        const int s = t >> 1, ci0 = (t & 1) << 5;
        const int kh = s / 3, kw = s - kh * 3;
        half8 a = *(const half8*)(wb + (t * 64 + L) * 8);
        #pragma unroll
        for (int ni = 0; ni < 4; ++ni) {
            const int row = wv * 4 + ni + kh, col = l15 + kw;
            half8 bfr = *(const half8*)(&s_in[(row * 18 + col) * 72 + ci0 + quad * 8]);
            acc[ni] = __builtin_amdgcn_mfma_f32_16x16x32_f16(a, bfr, acc[ni], 0, 0, 0);
        }
    }

    if (quad == 0) {
        float sc[3], bs[3];
        #pragma unroll
        for (int co = 0; co < 3; ++co) {
            sc[co] = g[co] * rsqrtf(bv[co] + EPS);
            bs[co] = (bconv[co] - bm[co]) * sc[co] + be[co];
        }
        #pragma unroll
        for (int ni = 0; ni < 4; ++ni) {
            const int h = h0 + wv * 4 + ni, wc = w0 + l15;
            #pragma unroll
            for (int co = 0; co < 3; ++co) {
                float val = selu_f(acc[ni][co] * sc[co] + bs[co]);
                const float* Xc = X + ((size_t)(b * 3 + co) << 16);
                float x = Xc[(h << 8) + wc];
                float res;
                if (x == 0.f) {
                    float lft = (wc > 0)   ? Xc[(h << 8) + wc - 1] : 0.f;
                    float rgt = (wc < 255) ? Xc[(h << 8) + wc + 1] : 0.f;
                    float top = (h > 0)    ? Xc[((h - 1) << 8) + wc] : 0.f;
                    float bot = (h < 255)  ? Xc[((h + 1) << 8) + wc] : 0.f;
                    float sm = lft + rgt + top + bot;
                    int cnt = (lft > 0.f) + (rgt > 0.f) + (top > 0.f) + (bot > 0.f);
                    res = cnt > 0 ? sm / (float)cnt : 0.f;
                } else {
                    res = x;
                }
                out[((b * 3 + co) << 16) + (h << 8) + wc] = val + res;
            }
        }
    }
}

extern "C" void kernel_launch(void* const* d_in, const int* in_sizes, int n_in,
                              void* d_out, int out_size, void* d_ws, size_t ws_size,
                              hipStream_t stream) {
    (void)in_sizes; (void)n_in; (void)out_size; (void)ws_size;
    const float* X    = (const float*)d_in[0];
    const float* w_in = (const float*)d_in[1];
    const float* b_in = (const float*)d_in[2];
    const float* g_in = (const float*)d_in[3];
    const float* be_in= (const float*)d_in[4];
    const float* m_in = (const float*)d_in[5];
    const float* v_in = (const float*)d_in[6];
    const float* w_h  = (const float*)d_in[7];
    const float* b_h  = (const float*)d_in[8];
    const float* g_h  = (const float*)d_in[9];
    const float* be_h = (const float*)d_in[10];
    const float* m_h  = (const float*)d_in[11];
    const float* v_h  = (const float*)d_in[12];
    const float* w_o  = (const float*)d_in[13];
    const float* b_o  = (const float*)d_in[14];
    const float* g_o  = (const float*)d_in[15];
    const float* be_o = (const float*)d_in[16];
    const float* m_o  = (const float*)d_in[17];
    const float* v_o  = (const float*)d_in[18];
    float* out = (float*)d_out;

    // ws layout (fp16 elems): act0[2^24] act1[2^24] wb_h[36864] wb_in[2048] wb_out[9216]
    //                         zp[256] bar[1 x u32]
    _Float16* act0  = (_Float16*)d_ws;
    _Float16* act1  = act0 + ((size_t)1 << 24);
    _Float16* wb_h  = act1 + ((size_t)1 << 24);
    _Float16* wb_in = wb_h + 36864;
    _Float16* wb_out= wb_in + 2048;
    _Float16* zp    = wb_out + 9216;
    unsigned* bar   = (unsigned*)(zp + 256);

    dim3 grid(16, 16, 4), block(256);
    k_prep<<<188, 256, 0, stream>>>(w_h, w_in, w_o, wb_h, wb_in, wb_out, zp, bar);
    k_conv_in_mfma<<<grid, block, 0, stream>>>(X, wb_in, b_in, g_in, be_in, m_in, v_in, act0);
    k_hidden_all<<<256, 1024, 0, stream>>>(act0, act1, wb_h, b_h, g_h, be_h, m_h, v_h, zp, bar);
    // 18 layers (even count) -> final activations land in act0
    k_conv_out_mfma<<<grid, block, 0, stream>>>(act0, wb_out, b_o, g_o, be_o, m_o, v_o, X, out);
}

// Round 17
// 564.040 us; speedup vs baseline: 1.7755x; 1.7755x over previous
//
#include <hip/hip_runtime.h>

#define EPS 1e-5f
#define SELU_L 1.0507009873554805f
#define SELU_A 1.6732632423543772f
#define SELU_LA (SELU_L * SELU_A)

typedef _Float16 half8 __attribute__((ext_vector_type(8)));
typedef _Float16 half4 __attribute__((ext_vector_type(4)));
typedef float floatx4 __attribute__((ext_vector_type(4)));

__device__ __forceinline__ float selu_f(float x) {
    return x > 0.f ? SELU_L * x : SELU_LA * (__expf(x) - 1.f);
}

// async global->LDS, 16B per lane; LDS dest is wave-uniform base + lane*16
__device__ __forceinline__ void gload_lds16(const _Float16* g, _Float16* l) {
    __builtin_amdgcn_global_load_lds(
        (const __attribute__((address_space(1))) void*)g,
        (__attribute__((address_space(3))) void*)l, 16, 0, 0);
}

// ------------- weight swizzle prep: A-operand fragment order, fp16 -------------
// wb_h : [t=18][mi=4][L=64][j=8]  co = mi*16 + (L&15), ci = (t&1)*32 + (L>>4)*8 + j, s = t>>1
// wb_in: [mi=4][L=64][j=8]        k = (L>>4)*8+j -> s=k/3, ci=k%3 (k>=27 -> 0)
// wb_out:[t=18][L=64][j=8]        co = L&15 (valid <3), ci/s as wb_h
// zp   : 256 halves of zeros (OOB redirect target for global_load_lds staging)
__global__ __launch_bounds__(256) void k_prep(
    const float* __restrict__ w_h, const float* __restrict__ w_in,
    const float* __restrict__ w_out, _Float16* __restrict__ wb_h,
    _Float16* __restrict__ wb_in, _Float16* __restrict__ wb_out,
    _Float16* __restrict__ zp)
{
    int i = blockIdx.x * 256 + threadIdx.x;
    if (i < 256) zp[i] = (_Float16)0.f;  // zero page (ws is poisoned between runs)
    if (i < 36864) {
        int t = i >> 11;
        int rem = i & 2047;
        int mi = rem >> 9;
        int L = (rem >> 3) & 63;
        int j = i & 7;
        int co = mi * 16 + (L & 15);
        int ci = ((t & 1) << 5) + ((L >> 4) << 3) + j;
        int s = t >> 1;
        wb_h[i] = (_Float16)w_h[(co * 64 + ci) * 9 + s];
    } else if (i < 36864 + 2048) {
        int e = i - 36864;
        int mi = e >> 9;
        int L = (e >> 3) & 63;
        int j = e & 7;
        int co = mi * 16 + (L & 15);
        int k = ((L >> 4) << 3) + j;
        _Float16 val = (_Float16)0.f;
        if (k < 27) {
            int s = k / 3, ci = k - s * 3;
            val = (_Float16)w_in[(co * 3 + ci) * 9 + s];
        }
        wb_in[e] = val;
    } else if (i < 36864 + 2048 + 9216) {
        int e = i - 36864 - 2048;
        int t = e >> 9;
        int L = (e >> 3) & 63;
        int j = e & 7;
        int co = L & 15;
        int ci = ((t & 1) << 5) + ((L >> 4) << 3) + j;
        int s = t >> 1;
        _Float16 val = (_Float16)0.f;
        if (co < 3) val = (_Float16)w_out[(co * 64 + ci) * 9 + s];
        wb_out[e] = val;
    }
}

// ------------- conv_in: 3 -> 64, BN, SELU, NHWC fp16 out (MFMA, K=32) -------------
__global__ __launch_bounds__(256) void k_conv_in_mfma(
    const float* __restrict__ X, const _Float16* __restrict__ wb,
    const float* __restrict__ bconv, const float* __restrict__ g,
    const float* __restrict__ be, const float* __restrict__ bm,
    const float* __restrict__ bv, _Float16* __restrict__ dst)
{
    __shared__ float s_x[3][18][18];
    __shared__ float s_sc[64], s_bs[64];
    const int tid = threadIdx.x;
    const int w0 = blockIdx.x * 16, h0 = blockIdx.y * 16, b = blockIdx.z;

    if (tid < 64) {
        float sc = g[tid] * rsqrtf(bv[tid] + EPS);
        s_sc[tid] = sc;
        s_bs[tid] = (bconv[tid] - bm[tid]) * sc + be[tid];
    }
    for (int idx = tid; idx < 3 * 324; idx += 256) {
        int ci = idx / 324, rem = idx - ci * 324;
        int r = rem / 18, c = rem - r * 18;
        int gh = h0 - 1 + r, gw = w0 - 1 + c;
        float val = 0.f;
        if ((unsigned)gh < 256u && (unsigned)gw < 256u)
            val = X[((b * 3 + ci) << 16) + (gh << 8) + gw];
        s_x[ci][r][c] = val;
    }
    __syncthreads();

    const int wv = tid >> 6, L = tid & 63, quad = L >> 4, l15 = L & 15;
    half8 a[4];
    #pragma unroll
    for (int mi = 0; mi < 4; ++mi)
        a[mi] = *(const half8*)(wb + (mi * 64 + L) * 8);

    floatx4 acc[4][4];
    #pragma unroll
    for (int mi = 0; mi < 4; ++mi)
        #pragma unroll
        for (int ni = 0; ni < 4; ++ni) acc[mi][ni] = (floatx4){0.f, 0.f, 0.f, 0.f};

    #pragma unroll
    for (int ni = 0; ni < 4; ++ni) {
        half8 bfr;
        #pragma unroll
        for (int j = 0; j < 8; ++j) {
            int k = quad * 8 + j;
            float xv = 0.f;
            if (k < 27) {
                int s = k / 3, ci = k - s * 3;
                int kh = s / 3, kw = s - kh * 3;
                xv = s_x[ci][wv * 4 + ni + kh][l15 + kw];
            }
            bfr[j] = (_Float16)xv;
        }
        #pragma unroll
        for (int mi = 0; mi < 4; ++mi)
            acc[mi][ni] = __builtin_amdgcn_mfma_f32_16x16x32_f16(a[mi], bfr, acc[mi][ni], 0, 0, 0);
    }

    _Float16* db = dst + ((size_t)b << 22);  // b*256*256*64
    #pragma unroll
    for (int mi = 0; mi < 4; ++mi) {
        const int cob = mi * 16 + quad * 4;
        floatx4 sc = *(const floatx4*)(&s_sc[cob]);
        floatx4 bs = *(const floatx4*)(&s_bs[cob]);
        #pragma unroll
        for (int ni = 0; ni < 4; ++ni) {
            half4 ov;
            #pragma unroll
            for (int r = 0; r < 4; ++r)
                ov[r] = (_Float16)selu_f(acc[mi][ni][r] * sc[r] + bs[r]);
            const int row = h0 + wv * 4 + ni, col = w0 + l15;
            *(half4*)(db + ((((row << 8) + col) << 6) + cob)) = ov;
        }
    }
}

// ------------- hidden v14: v9 (best, 594 us) + XCD-aware block swizzle ----------------
// (round 16 post-mortem: mega-kernel barrier cost ~21 us/layer with AND without the
//  poll storm -> it's the intrinsic cross-XCD coherence drain (L2 writeback on the
//  release fence, serialized); kernel boundaries do the same work overlapped by the
//  CP. Fusion abandoned; revert to v9. Remaining counter evidence: FETCH 19.3 MB/
//  dispatch = 58% of act re-reads miss L2 — consecutive blockIdx round-robins XCDs,
//  so halo rows live on other XCDs and per-XCD working sets aren't clustered.
//  Swizzle swz=(x&7)*32+(x>>3) (bijective 8x32 transpose): XCD g owns 128 contiguous
//  tiles (8-tile-row band), launch-stable across layers -> halo same-XCD, stage
//  bursts mostly L2-local. Pure index permutation; compute byte-identical v9.)
__global__ __launch_bounds__(1024) void k_hidden_v14(
    const _Float16* __restrict__ src, const _Float16* __restrict__ wb,
    const float* __restrict__ bconv, const float* __restrict__ g,
    const float* __restrict__ be, const float* __restrict__ bm,
    const float* __restrict__ bv, const _Float16* __restrict__ zp,
    _Float16* __restrict__ dst)
{
    __shared__ _Float16 s_w[36864];        // 73728 B: full weight set
    __shared__ _Float16 s_act[2][20992];   // 2 x 41984 B (41 wave-chunks incl. pad)
    __shared__ float s_sc[64], s_bs[64];
    const int tid = threadIdx.x;
    const int wv = tid >> 6, L = tid & 63, quad = L >> 4, l15 = L & 15;
    const int rh = wv >> 1, mh = wv & 1;   // row-pair (0..7), channel-half

    if (tid < 64) {
        float sc = g[tid] * rsqrtf(bv[tid] + EPS);
        s_sc[tid] = sc;
        s_bs[tid] = (bconv[tid] - bm[tid]) * sc + be[tid];
    }

    // ---- weights -> LDS once per block: 72 wave-chunks x 1 KB over 16 waves ----
    #pragma unroll
    for (int k = 0; k < 5; ++k) {
        const int wc = k * 16 + wv;
        if (wc < 72)
            gload_lds16(wb + ((wc << 6) + L) * 8, &s_w[wc << 9]);
    }

    // ---- stage one 18x18x64 halo tile (41 wave-chunks) over 16 waves ----
    auto stage = [&](int tau, int buf) {
        const int b = tau >> 8, rem = tau & 255;
        const int h0 = (rem >> 4) << 4, w0 = (rem & 15) << 4;
        const _Float16* sb = src + ((size_t)b << 22);
        #pragma unroll
        for (int k = 0; k < 3; ++k) {
            const int wc = k * 16 + wv;          // wave-uniform
            if (wc < 41) {
                const int p = (wc << 3) + (L >> 3);   // pixel (>=324 is pad)
                const int sd = (L & 7) ^ (p & 7);     // source chunk (pre-swizzle)
                const int rp = p / 18, cl = p - rp * 18;
                const int gh = h0 - 1 + rp, gw = w0 - 1 + cl;
                const _Float16* gp = (p < 324 && (unsigned)gh < 256u && (unsigned)gw < 256u)
                    ? sb + ((((gh << 8) + gw) << 6) + (sd << 3)) : zp;
                gload_lds16(gp, &s_act[buf][wc << 9]);
            }
        }
    };

    // XCD-aware swizzle: HW assigns XCD by blockIdx%8; remap so XCD g gets 32
    // consecutive logical groups = 128 contiguous tiles (8-tile-row band, stable
    // across layers). Bijective transpose of 8x32.
    const int swz = ((blockIdx.x & 7) << 5) + (blockIdx.x >> 3);
    const int tau0 = swz << 2;          // 4 consecutive tiles (shared halo -> L2 hits)
    stage(tau0, 0);
    __syncthreads();   // drains vmcnt: weights + tile0 staging complete

    for (int ti = 0; ti < 4; ++ti) {
        const int tau = tau0 + ti, cur = ti & 1;
        if (ti < 3) stage(tau + 1, cur ^ 1);   // issue-early: latency hides under MFMA

        floatx4 acc[2][2];
        #pragma unroll
        for (int m = 0; m < 2; ++m)
            #pragma unroll
            for (int ni = 0; ni < 2; ++ni) acc[m][ni] = (floatx4){0.f, 0.f, 0.f, 0.f};

        const _Float16* bufp = &s_act[cur][0];
        #pragma unroll
        for (int h = 0; h < 2; ++h) {          // k-half (ci 0-31 / 32-63)
            const int sb8 = (h << 2) + quad;   // chunk slot within pixel
            #pragma unroll
            for (int kw = 0; kw < 3; ++kw) {
                half8 ac[3][2];                // A-cache: 3 kh x 2 m
                #pragma unroll
                for (int kh = 0; kh < 3; ++kh) {
                    const int t = ((kh * 3 + kw) << 1) + h;
                    ac[kh][0] = *(const half8*)(&s_w[((t * 4 + mh * 2 + 0) * 64 + L) * 8]);
                    ac[kh][1] = *(const half8*)(&s_w[((t * 4 + mh * 2 + 1) * 64 + L) * 8]);
                }
                #pragma unroll
                for (int j = 0; j < 4; ++j) {  // one B-read feeds up to 6 MFMAs
                    const int p = (rh * 2 + j) * 18 + l15 + kw;
                    half8 bfr = *(const half8*)(bufp + (p << 6) + (((p & 7) ^ sb8) << 3));
                    #pragma unroll
                    for (int kh = 0; kh < 3; ++kh) {
                        const int ni = j - kh;
                        if (ni >= 0 && ni < 2) {
                            acc[0][ni] = __builtin_amdgcn_mfma_f32_16x16x32_f16(ac[kh][0], bfr, acc[0][ni], 0, 0, 0);
                            acc[1][ni] = __builtin_amdgcn_mfma_f32_16x16x32_f16(ac[kh][1], bfr, acc[1][ni], 0, 0, 0);
                        }
                    }
                }
            }
        }

        // epilogue: BN + SELU + NHWC store
        const int b = tau >> 8, rem = tau & 255;
        const int h0 = (rem >> 4) << 4, w0 = (rem & 15) << 4;
        _Float16* db = dst + ((size_t)b << 22);
        #pragma unroll
        for (int m = 0; m < 2; ++m) {
            const int cob = (mh * 2 + m) * 16 + quad * 4;
            floatx4 sc = *(const floatx4*)(&s_sc[cob]);
            floatx4 bs = *(const floatx4*)(&s_bs[cob]);
            #pragma unroll
            for (int ni = 0; ni < 2; ++ni) {
                half4 ov;
                #pragma unroll
                for (int r = 0; r < 4; ++r)
                    ov[r] = (_Float16)selu_f(acc[m][ni][r] * sc[r] + bs[r]);
                const int row = h0 + rh * 2 + ni, col = w0 + l15;
                *(half4*)(db + ((((row << 8) + col) << 6) + cob)) = ov;
            }
        }
        __syncthreads();   // all waves done with buf[cur]; next iter may overwrite it
    }
}

// ------------- conv_out: 64 -> 3, BN, SELU, + interpolate_zeros(X), fp32 out -------------
__global__ __launch_bounds__(256) void k_conv_out_mfma(
    const _Float16* __restrict__ src, const _Float16* __restrict__ wb,
    const float* __restrict__ bconv, const float* __restrict__ g,
    const float* __restrict__ be, const float* __restrict__ bm,
    const float* __restrict__ bv, const float* __restrict__ X,
    float* __restrict__ out)
{
    __shared__ _Float16 s_in[324 * 72];
    const int tid = threadIdx.x;
    const int w0 = blockIdx.x * 16, h0 = blockIdx.y * 16, b = blockIdx.z;
    const _Float16* sb = src + ((size_t)b << 22);

    for (int idx = tid; idx < 2592; idx += 256) {
        int r = idx / 144, cpos = idx - r * 144;
        int col = cpos >> 3, sub = cpos & 7;
        int gh = h0 - 1 + r, gw = w0 - 1 + col;
        half8 val = {0, 0, 0, 0, 0, 0, 0, 0};
        if ((unsigned)gh < 256u && (unsigned)gw < 256u)
            val = *(const half8*)(sb + ((((gh << 8) + gw) << 6) + (sub << 3)));
        *(half8*)(&s_in[(r * 18 + col) * 72 + (sub << 3)]) = val;
    }
    __syncthreads();

    const int wv = tid >> 6, L = tid & 63, quad = L >> 4, l15 = L & 15;
    floatx4 acc[4];
    #pragma unroll
    for (int ni = 0; ni < 4; ++ni) acc[ni] = (floatx4){0.f, 0.f, 0.f, 0.f};

    #pragma unroll
    for (int t = 0; t < 18; ++t) {
        const int s = t >> 1, ci0 = (t & 1) << 5;
        const int kh = s / 3, kw = s - kh * 3;
        half8 a = *(const half8*)(wb + (t * 64 + L) * 8);
        #pragma unroll
        for (int ni = 0; ni < 4; ++ni) {
            const int row = wv * 4 + ni + kh, col = l15 + kw;
            half8 bfr = *(const half8*)(&s_in[(row * 18 + col) * 72 + ci0 + quad * 8]);
            acc[ni] = __builtin_amdgcn_mfma_f32_16x16x32_f16(a, bfr, acc[ni], 0, 0, 0);
        }
    }

    if (quad == 0) {
        float sc[3], bs[3];
        #pragma unroll
        for (int co = 0; co < 3; ++co) {
            sc[co] = g[co] * rsqrtf(bv[co] + EPS);
            bs[co] = (bconv[co] - bm[co]) * sc[co] + be[co];
        }
        #pragma unroll
        for (int ni = 0; ni < 4; ++ni) {
            const int h = h0 + wv * 4 + ni, wc = w0 + l15;
            #pragma unroll
            for (int co = 0; co < 3; ++co) {
                float val = selu_f(acc[ni][co] * sc[co] + bs[co]);
                const float* Xc = X + ((size_t)(b * 3 + co) << 16);
                float x = Xc[(h << 8) + wc];
                float res;
                if (x == 0.f) {
                    float lft = (wc > 0)   ? Xc[(h << 8) + wc - 1] : 0.f;
                    float rgt = (wc < 255) ? Xc[(h << 8) + wc + 1] : 0.f;
                    float top = (h > 0)    ? Xc[((h - 1) << 8) + wc] : 0.f;
                    float bot = (h < 255)  ? Xc[((h + 1) << 8) + wc] : 0.f;
                    float sm = lft + rgt + top + bot;
                    int cnt = (lft > 0.f) + (rgt > 0.f) + (top > 0.f) + (bot > 0.f);
                    res = cnt > 0 ? sm / (float)cnt : 0.f;
                } else {
                    res = x;
                }
                out[((b * 3 + co) << 16) + (h << 8) + wc] = val + res;
            }
        }
    }
}

extern "C" void kernel_launch(void* const* d_in, const int* in_sizes, int n_in,
                              void* d_out, int out_size, void* d_ws, size_t ws_size,
                              hipStream_t stream) {
    (void)in_sizes; (void)n_in; (void)out_size; (void)ws_size;
    const float* X    = (const float*)d_in[0];
    const float* w_in = (const float*)d_in[1];
    const float* b_in = (const float*)d_in[2];
    const float* g_in = (const float*)d_in[3];
    const float* be_in= (const float*)d_in[4];
    const float* m_in = (const float*)d_in[5];
    const float* v_in = (const float*)d_in[6];
    const float* w_h  = (const float*)d_in[7];
    const float* b_h  = (const float*)d_in[8];
    const float* g_h  = (const float*)d_in[9];
    const float* be_h = (const float*)d_in[10];
    const float* m_h  = (const float*)d_in[11];
    const float* v_h  = (const float*)d_in[12];
    const float* w_o  = (const float*)d_in[13];
    const float* b_o  = (const float*)d_in[14];
    const float* g_o  = (const float*)d_in[15];
    const float* be_o = (const float*)d_in[16];
    const float* m_o  = (const float*)d_in[17];
    const float* v_o  = (const float*)d_in[18];
    float* out = (float*)d_out;

    // ws layout (fp16 elems): act0[2^24] act1[2^24] wb_h[36864] wb_in[2048] wb_out[9216] zp[256]
    _Float16* act0  = (_Float16*)d_ws;
    _Float16* act1  = act0 + ((size_t)1 << 24);
    _Float16* wb_h  = act1 + ((size_t)1 << 24);
    _Float16* wb_in = wb_h + 36864;
    _Float16* wb_out= wb_in + 2048;
    _Float16* zp    = wb_out + 9216;

    dim3 grid(16, 16, 4), block(256);
    k_prep<<<188, 256, 0, stream>>>(w_h, w_in, w_o, wb_h, wb_in, wb_out, zp);
    k_conv_in_mfma<<<grid, block, 0, stream>>>(X, wb_in, b_in, g_in, be_in, m_in, v_in, act0);
    _Float16* src = act0;
    _Float16* dst = act1;
    for (int i = 0; i < 18; ++i) {
        k_hidden_v14<<<256, 1024, 0, stream>>>(src, wb_h, b_h, g_h, be_h, m_h, v_h, zp, dst);
        _Float16* t = src; src = dst; dst = t;
    }
    k_conv_out_mfma<<<grid, block, 0, stream>>>(src, wb_out, b_o, g_o, be_o, m_o, v_o, X, out);
}

// Round 18
// 552.955 us; speedup vs baseline: 1.8111x; 1.0200x over previous
//
#include <hip/hip_runtime.h>

#define EPS 1e-5f
#define SELU_L 1.0507009873554805f
#define SELU_A 1.6732632423543772f
#define SELU_LA (SELU_L * SELU_A)

typedef _Float16 half8 __attribute__((ext_vector_type(8)));
typedef _Float16 half4 __attribute__((ext_vector_type(4)));
typedef float floatx4 __attribute__((ext_vector_type(4)));

__device__ __forceinline__ float selu_f(float x) {
    return x > 0.f ? SELU_L * x : SELU_LA * (__expf(x) - 1.f);
}

// async global->LDS, 16B per lane; LDS dest is wave-uniform base + lane*16
__device__ __forceinline__ void gload_lds16(const _Float16* g, _Float16* l) {
    __builtin_amdgcn_global_load_lds(
        (const __attribute__((address_space(1))) void*)g,
        (__attribute__((address_space(3))) void*)l, 16, 0, 0);
}

// ------------- weight swizzle prep: A-operand fragment order, fp16 -------------
// wb_h : [t=18][mi=4][L=64][j=8]  co = mi*16 + (L&15), ci = (t&1)*32 + (L>>4)*8 + j, s = t>>1
// wb_in: [mi=4][L=64][j=8]        k = (L>>4)*8+j -> s=k/3, ci=k%3 (k>=27 -> 0)
// wb_out:[t=18][L=64][j=8]        co = L&15 (valid <3), ci/s as wb_h
// zp   : 256 halves of zeros (OOB redirect target for global_load_lds staging)
__global__ __launch_bounds__(256) void k_prep(
    const float* __restrict__ w_h, const float* __restrict__ w_in,
    const float* __restrict__ w_out, _Float16* __restrict__ wb_h,
    _Float16* __restrict__ wb_in, _Float16* __restrict__ wb_out,
    _Float16* __restrict__ zp)
{
    int i = blockIdx.x * 256 + threadIdx.x;
    if (i < 256) zp[i] = (_Float16)0.f;  // zero page (ws is poisoned between runs)
    if (i < 36864) {
        int t = i >> 11;
        int rem = i & 2047;
        int mi = rem >> 9;
        int L = (rem >> 3) & 63;
        int j = i & 7;
        int co = mi * 16 + (L & 15);
        int ci = ((t & 1) << 5) + ((L >> 4) << 3) + j;
        int s = t >> 1;
        wb_h[i] = (_Float16)w_h[(co * 64 + ci) * 9 + s];
    } else if (i < 36864 + 2048) {
        int e = i - 36864;
        int mi = e >> 9;
        int L = (e >> 3) & 63;
        int j = e & 7;
        int co = mi * 16 + (L & 15);
        int k = ((L >> 4) << 3) + j;
        _Float16 val = (_Float16)0.f;
        if (k < 27) {
            int s = k / 3, ci = k - s * 3;
            val = (_Float16)w_in[(co * 3 + ci) * 9 + s];
        }
        wb_in[e] = val;
    } else if (i < 36864 + 2048 + 9216) {
        int e = i - 36864 - 2048;
        int t = e >> 9;
        int L = (e >> 3) & 63;
        int j = e & 7;
        int co = L & 15;
        int ci = ((t & 1) << 5) + ((L >> 4) << 3) + j;
        int s = t >> 1;
        _Float16 val = (_Float16)0.f;
        if (co < 3) val = (_Float16)w_out[(co * 64 + ci) * 9 + s];
        wb_out[e] = val;
    }
}

// ------------- conv_in: 3 -> 64, BN, SELU, NHWC fp16 out (MFMA, K=32) -------------
// (round 17: 1D grid + XCD-band tile decode — writes act0 in the same XCD bands the
//  hidden layers read: tau = (bid&7)*128 + (bid>>3), b = tau>>8, rem = tau&255.)
__global__ __launch_bounds__(256) void k_conv_in_mfma(
    const float* __restrict__ X, const _Float16* __restrict__ wb,
    const float* __restrict__ bconv, const float* __restrict__ g,
    const float* __restrict__ be, const float* __restrict__ bm,
    const float* __restrict__ bv, _Float16* __restrict__ dst)
{
    __shared__ float s_x[3][18][18];
    __shared__ float s_sc[64], s_bs[64];
    const int tid = threadIdx.x;
    const int tau = ((blockIdx.x & 7) << 7) + (blockIdx.x >> 3);   // XCD band
    const int b = tau >> 8, rem = tau & 255;
    const int h0 = (rem >> 4) << 4, w0 = (rem & 15) << 4;

    if (tid < 64) {
        float sc = g[tid] * rsqrtf(bv[tid] + EPS);
        s_sc[tid] = sc;
        s_bs[tid] = (bconv[tid] - bm[tid]) * sc + be[tid];
    }
    for (int idx = tid; idx < 3 * 324; idx += 256) {
        int ci = idx / 324, rem2 = idx - ci * 324;
        int r = rem2 / 18, c = rem2 - r * 18;
        int gh = h0 - 1 + r, gw = w0 - 1 + c;
        float val = 0.f;
        if ((unsigned)gh < 256u && (unsigned)gw < 256u)
            val = X[((b * 3 + ci) << 16) + (gh << 8) + gw];
        s_x[ci][r][c] = val;
    }
    __syncthreads();

    const int wv = tid >> 6, L = tid & 63, quad = L >> 4, l15 = L & 15;
    half8 a[4];
    #pragma unroll
    for (int mi = 0; mi < 4; ++mi)
        a[mi] = *(const half8*)(wb + (mi * 64 + L) * 8);

    floatx4 acc[4][4];
    #pragma unroll
    for (int mi = 0; mi < 4; ++mi)
        #pragma unroll
        for (int ni = 0; ni < 4; ++ni) acc[mi][ni] = (floatx4){0.f, 0.f, 0.f, 0.f};

    #pragma unroll
    for (int ni = 0; ni < 4; ++ni) {
        half8 bfr;
        #pragma unroll
        for (int j = 0; j < 8; ++j) {
            int k = quad * 8 + j;
            float xv = 0.f;
            if (k < 27) {
                int s = k / 3, ci = k - s * 3;
                int kh = s / 3, kw = s - kh * 3;
                xv = s_x[ci][wv * 4 + ni + kh][l15 + kw];
            }
            bfr[j] = (_Float16)xv;
        }
        #pragma unroll
        for (int mi = 0; mi < 4; ++mi)
            acc[mi][ni] = __builtin_amdgcn_mfma_f32_16x16x32_f16(a[mi], bfr, acc[mi][ni], 0, 0, 0);
    }

    _Float16* db = dst + ((size_t)b << 22);  // b*256*256*64
    #pragma unroll
    for (int mi = 0; mi < 4; ++mi) {
        const int cob = mi * 16 + quad * 4;
        floatx4 sc = *(const floatx4*)(&s_sc[cob]);
        floatx4 bs = *(const floatx4*)(&s_bs[cob]);
        #pragma unroll
        for (int ni = 0; ni < 4; ++ni) {
            half4 ov;
            #pragma unroll
            for (int r = 0; r < 4; ++r)
                ov[r] = (_Float16)selu_f(acc[mi][ni][r] * sc[r] + bs[r]);
            const int row = h0 + wv * 4 + ni, col = w0 + l15;
            *(half4*)(db + ((((row << 8) + col) << 6) + cob)) = ov;
        }
    }
}

// ------------- hidden v14: v9 + XCD-aware block swizzle (BEST: 564 us) ----------------
// (round 16/17: swizzle swz=(x&7)*32+(x>>3) gives each XCD a 128-tile contiguous band,
//  stable across layers -> halo + act round-trip same-XCD; +5% verified. Compute is
//  the v9 16-wave partition; traffic-invariance of rounds 11-15 nulls shows the bound
//  is the serialized per-layer memory round-trip, so only locality levers pay.)
__global__ __launch_bounds__(1024) void k_hidden_v14(
    const _Float16* __restrict__ src, const _Float16* __restrict__ wb,
    const float* __restrict__ bconv, const float* __restrict__ g,
    const float* __restrict__ be, const float* __restrict__ bm,
    const float* __restrict__ bv, const _Float16* __restrict__ zp,
    _Float16* __restrict__ dst)
{
    __shared__ _Float16 s_w[36864];        // 73728 B: full weight set
    __shared__ _Float16 s_act[2][20992];   // 2 x 41984 B (41 wave-chunks incl. pad)
    __shared__ float s_sc[64], s_bs[64];
    const int tid = threadIdx.x;
    const int wv = tid >> 6, L = tid & 63, quad = L >> 4, l15 = L & 15;
    const int rh = wv >> 1, mh = wv & 1;   // row-pair (0..7), channel-half

    if (tid < 64) {
        float sc = g[tid] * rsqrtf(bv[tid] + EPS);
        s_sc[tid] = sc;
        s_bs[tid] = (bconv[tid] - bm[tid]) * sc + be[tid];
    }

    // ---- weights -> LDS once per block: 72 wave-chunks x 1 KB over 16 waves ----
    #pragma unroll
    for (int k = 0; k < 5; ++k) {
        const int wc = k * 16 + wv;
        if (wc < 72)
            gload_lds16(wb + ((wc << 6) + L) * 8, &s_w[wc << 9]);
    }

    // ---- stage one 18x18x64 halo tile (41 wave-chunks) over 16 waves ----
    auto stage = [&](int tau, int buf) {
        const int b = tau >> 8, rem = tau & 255;
        const int h0 = (rem >> 4) << 4, w0 = (rem & 15) << 4;
        const _Float16* sb = src + ((size_t)b << 22);
        #pragma unroll
        for (int k = 0; k < 3; ++k) {
            const int wc = k * 16 + wv;          // wave-uniform
            if (wc < 41) {
                const int p = (wc << 3) + (L >> 3);   // pixel (>=324 is pad)
                const int sd = (L & 7) ^ (p & 7);     // source chunk (pre-swizzle)
                const int rp = p / 18, cl = p - rp * 18;
                const int gh = h0 - 1 + rp, gw = w0 - 1 + cl;
                const _Float16* gp = (p < 324 && (unsigned)gh < 256u && (unsigned)gw < 256u)
                    ? sb + ((((gh << 8) + gw) << 6) + (sd << 3)) : zp;
                gload_lds16(gp, &s_act[buf][wc << 9]);
            }
        }
    };

    // XCD-aware swizzle: XCD g owns 32 consecutive logical groups = 128 contiguous
    // tiles (8-tile-row band, stable across layers). Bijective transpose of 8x32.
    const int swz = ((blockIdx.x & 7) << 5) + (blockIdx.x >> 3);
    const int tau0 = swz << 2;          // 4 consecutive tiles (shared halo -> L2 hits)
    stage(tau0, 0);
    __syncthreads();   // drains vmcnt: weights + tile0 staging complete

    for (int ti = 0; ti < 4; ++ti) {
        const int tau = tau0 + ti, cur = ti & 1;
        if (ti < 3) stage(tau + 1, cur ^ 1);   // issue-early: latency hides under MFMA

        floatx4 acc[2][2];
        #pragma unroll
        for (int m = 0; m < 2; ++m)
            #pragma unroll
            for (int ni = 0; ni < 2; ++ni) acc[m][ni] = (floatx4){0.f, 0.f, 0.f, 0.f};

        const _Float16* bufp = &s_act[cur][0];
        #pragma unroll
        for (int h = 0; h < 2; ++h) {          // k-half (ci 0-31 / 32-63)
            const int sb8 = (h << 2) + quad;   // chunk slot within pixel
            #pragma unroll
            for (int kw = 0; kw < 3; ++kw) {
                half8 ac[3][2];                // A-cache: 3 kh x 2 m
                #pragma unroll
                for (int kh = 0; kh < 3; ++kh) {
                    const int t = ((kh * 3 + kw) << 1) + h;
                    ac[kh][0] = *(const half8*)(&s_w[((t * 4 + mh * 2 + 0) * 64 + L) * 8]);
                    ac[kh][1] = *(const half8*)(&s_w[((t * 4 + mh * 2 + 1) * 64 + L) * 8]);
                }
                #pragma unroll
                for (int j = 0; j < 4; ++j) {  // one B-read feeds up to 6 MFMAs
                    const int p = (rh * 2 + j) * 18 + l15 + kw;
                    half8 bfr = *(const half8*)(bufp + (p << 6) + (((p & 7) ^ sb8) << 3));
                    #pragma unroll
                    for (int kh = 0; kh < 3; ++kh) {
                        const int ni = j - kh;
                        if (ni >= 0 && ni < 2) {
                            acc[0][ni] = __builtin_amdgcn_mfma_f32_16x16x32_f16(ac[kh][0], bfr, acc[0][ni], 0, 0, 0);
                            acc[1][ni] = __builtin_amdgcn_mfma_f32_16x16x32_f16(ac[kh][1], bfr, acc[1][ni], 0, 0, 0);
                        }
                    }
                }
            }
        }

        // epilogue: BN + SELU + NHWC store
        const int b = tau >> 8, rem = tau & 255;
        const int h0 = (rem >> 4) << 4, w0 = (rem & 15) << 4;
        _Float16* db = dst + ((size_t)b << 22);
        #pragma unroll
        for (int m = 0; m < 2; ++m) {
            const int cob = (mh * 2 + m) * 16 + quad * 4;
            floatx4 sc = *(const floatx4*)(&s_sc[cob]);
            floatx4 bs = *(const floatx4*)(&s_bs[cob]);
            #pragma unroll
            for (int ni = 0; ni < 2; ++ni) {
                half4 ov;
                #pragma unroll
                for (int r = 0; r < 4; ++r)
                    ov[r] = (_Float16)selu_f(acc[m][ni][r] * sc[r] + bs[r]);
                const int row = h0 + rh * 2 + ni, col = w0 + l15;
                *(half4*)(db + ((((row << 8) + col) << 6) + cob)) = ov;
            }
        }
        __syncthreads();   // all waves done with buf[cur]; next iter may overwrite it
    }
}

// ------------- conv_out: 64 -> 3, BN, SELU, + interpolate_zeros(X), fp32 out -------------
// (round 17: 1D grid + XCD-band tile decode — reads the last hidden layer's banded
//  writes same-XCD.)
__global__ __launch_bounds__(256) void k_conv_out_mfma(
    const _Float16* __restrict__ src, const _Float16* __restrict__ wb,
    const float* __restrict__ bconv, const float* __restrict__ g,
    const float* __restrict__ be, const float* __restrict__ bm,
    const float* __restrict__ bv, const float* __restrict__ X,
    float* __restrict__ out)
{
    __shared__ _Float16 s_in[324 * 72];
    const int tid = threadIdx.x;
    const int tau = ((blockIdx.x & 7) << 7) + (blockIdx.x >> 3);   // XCD band
    const int b = tau >> 8, rem = tau & 255;
    const int h0 = (rem >> 4) << 4, w0 = (rem & 15) << 4;
    const _Float16* sb = src + ((size_t)b << 22);

    for (int idx = tid; idx < 2592; idx += 256) {
        int r = idx / 144, cpos = idx - r * 144;
        int col = cpos >> 3, sub = cpos & 7;
        int gh = h0 - 1 + r, gw = w0 - 1 + col;
        half8 val = {0, 0, 0, 0, 0, 0, 0, 0};
        if ((unsigned)gh < 256u && (unsigned)gw < 256u)
            val = *(const half8*)(sb + ((((gh << 8) + gw) << 6) + (sub << 3)));
        *(half8*)(&s_in[(r * 18 + col) * 72 + (sub << 3)]) = val;
    }
    __syncthreads();

    const int wv = tid >> 6, L = tid & 63, quad = L >> 4, l15 = L & 15;
    floatx4 acc[4];
    #pragma unroll
    for (int ni = 0; ni < 4; ++ni) acc[ni] = (floatx4){0.f, 0.f, 0.f, 0.f};

    #pragma unroll
    for (int t = 0; t < 18; ++t) {
        const int s = t >> 1, ci0 = (t & 1) << 5;
        const int kh = s / 3, kw = s - kh * 3;
        half8 a = *(const half8*)(wb + (t * 64 + L) * 8);
        #pragma unroll
        for (int ni = 0; ni < 4; ++ni) {
            const int row = wv * 4 + ni + kh, col = l15 + kw;
            half8 bfr = *(const half8*)(&s_in[(row * 18 + col) * 72 + ci0 + quad * 8]);
            acc[ni] = __builtin_amdgcn_mfma_f32_16x16x32_f16(a, bfr, acc[ni], 0, 0, 0);
        }
    }

    if (quad == 0) {
        float sc[3], bs[3];
        #pragma unroll
        for (int co = 0; co < 3; ++co) {
            sc[co] = g[co] * rsqrtf(bv[co] + EPS);
            bs[co] = (bconv[co] - bm[co]) * sc[co] + be[co];
        }
        #pragma unroll
        for (int ni = 0; ni < 4; ++ni) {
            const int h = h0 + wv * 4 + ni, wc = w0 + l15;
            #pragma unroll
            for (int co = 0; co < 3; ++co) {
                float val = selu_f(acc[ni][co] * sc[co] + bs[co]);
                const float* Xc = X + ((size_t)(b * 3 + co) << 16);
                float x = Xc[(h << 8) + wc];
                float res;
                if (x == 0.f) {
                    float lft = (wc > 0)   ? Xc[(h << 8) + wc - 1] : 0.f;
                    float rgt = (wc < 255) ? Xc[(h << 8) + wc + 1] : 0.f;
                    float top = (h > 0)    ? Xc[((h - 1) << 8) + wc] : 0.f;
                    float bot = (h < 255)  ? Xc[((h + 1) << 8) + wc] : 0.f;
                    float sm = lft + rgt + top + bot;
                    int cnt = (lft > 0.f) + (rgt > 0.f) + (top > 0.f) + (bot > 0.f);
                    res = cnt > 0 ? sm / (float)cnt : 0.f;
                } else {
                    res = x;
                }
                out[((b * 3 + co) << 16) + (h << 8) + wc] = val + res;
            }
        }
    }
}

extern "C" void kernel_launch(void* const* d_in, const int* in_sizes, int n_in,
                              void* d_out, int out_size, void* d_ws, size_t ws_size,
                              hipStream_t stream) {
    (void)in_sizes; (void)n_in; (void)out_size; (void)ws_size;
    const float* X    = (const float*)d_in[0];
    const float* w_in = (const float*)d_in[1];
    const float* b_in = (const float*)d_in[2];
    const float* g_in = (const float*)d_in[3];
    const float* be_in= (const float*)d_in[4];
    const float* m_in = (const float*)d_in[5];
    const float* v_in = (const float*)d_in[6];
    const float* w_h  = (const float*)d_in[7];
    const float* b_h  = (const float*)d_in[8];
    const float* g_h  = (const float*)d_in[9];
    const float* be_h = (const float*)d_in[10];
    const float* m_h  = (const float*)d_in[11];
    const float* v_h  = (const float*)d_in[12];
    const float* w_o  = (const float*)d_in[13];
    const float* b_o  = (const float*)d_in[14];
    const float* g_o  = (const float*)d_in[15];
    const float* be_o = (const float*)d_in[16];
    const float* m_o  = (const float*)d_in[17];
    const float* v_o  = (const float*)d_in[18];
    float* out = (float*)d_out;

    // ws layout (fp16 elems): act0[2^24] act1[2^24] wb_h[36864] wb_in[2048] wb_out[9216] zp[256]
    _Float16* act0  = (_Float16*)d_ws;
    _Float16* act1  = act0 + ((size_t)1 << 24);
    _Float16* wb_h  = act1 + ((size_t)1 << 24);
    _Float16* wb_in = wb_h + 36864;
    _Float16* wb_out= wb_in + 2048;
    _Float16* zp    = wb_out + 9216;

    k_prep<<<188, 256, 0, stream>>>(w_h, w_in, w_o, wb_h, wb_in, wb_out, zp);
    k_conv_in_mfma<<<1024, 256, 0, stream>>>(X, wb_in, b_in, g_in, be_in, m_in, v_in, act0);
    _Float16* src = act0;
    _Float16* dst = act1;
    for (int i = 0; i < 18; ++i) {
        k_hidden_v14<<<256, 1024, 0, stream>>>(src, wb_h, b_h, g_h, be_h, m_h, v_h, zp, dst);
        _Float16* t = src; src = dst; dst = t;
    }
    k_conv_out_mfma<<<1024, 256, 0, stream>>>(src, wb_out, b_o, g_o, be_o, m_o, v_o, X, out);
}